// Round 7
// baseline (347.834 us; speedup 1.0000x reference)
//
#include <hip/hip_runtime.h>
#include <hip/hip_bf16.h>

// Problem constants
#define B_LON 15      // NLON
#define NW    32      // TYPE_OF_WINDOWS
#define NTOK  144     // N_TOK
#define DIM   192
#define NH    6
#define HD    32
#define K3    576     // 3*DIM
#define MROWS (B_LON*NW*NTOK)   // 69120
#define NN    (NTOK*NTOK)       // 20736
#define SCALE 0.17677669529663687f  // 32^-0.5

typedef __attribute__((ext_vector_type(8))) short bf16x8;
typedef __attribute__((ext_vector_type(8))) unsigned short u16x8;
typedef __attribute__((ext_vector_type(4))) float f32x4;

__device__ inline unsigned short f2bf(float f) {
  __bf16 h = (__bf16)f;
  return __builtin_bit_cast(unsigned short, h);
}
__device__ inline float bf2f(unsigned short u) {
  union { unsigned int i; float f; } c;
  c.i = ((unsigned int)u) << 16;
  return c.f;
}

#define NQ8 13824     // 576*192/8
#define NP8 4608      // 192*192/8

// ---------------------------------------------------------------------------
// Kernel -1: fp32 -> bf16 pre-convert of qkv_w, proj_w (weights only now).
// ---------------------------------------------------------------------------
__global__ __launch_bounds__(256) void conv_bf_k(
    const float* __restrict__ qw, const float* __restrict__ pw,
    unsigned short* __restrict__ qwbf, unsigned short* __restrict__ pwbf) {
  const long gid = (long)blockIdx.x * 256 + threadIdx.x;
  const float* src;
  unsigned short* dst;
  long off;
  if (gid < NQ8) { src = qw; dst = qwbf; off = gid; }
  else           { src = pw; dst = pwbf; off = gid - NQ8; }
  const float4 a = ((const float4*)src)[off * 2];
  const float4 b = ((const float4*)src)[off * 2 + 1];
  u16x8 u = {f2bf(a.x), f2bf(a.y), f2bf(a.z), f2bf(a.w),
             f2bf(b.x), f2bf(b.y), f2bf(b.z), f2bf(b.w)};
  *(u16x8*)&dst[off * 8] = u;
}

// ---------------------------------------------------------------------------
// Kernel 0: bias precompute.  biasb[wh][ij] = bf16(btab[pos[ij]*192 + wh]).
// ---------------------------------------------------------------------------
__global__ __launch_bounds__(256) void bias_pre_k(
    const float* __restrict__ btab, const int* __restrict__ pos,
    unsigned short* __restrict__ biasb) {
  const int wh  = blockIdx.x;          // 0..191
  const int seg = blockIdx.y * 2304;   // 9 segs of 2304
  unsigned short* dst = biasb + (size_t)wh * NN;
#pragma unroll
  for (int it = 0; it < 9; ++it) {
    const int e = seg + it * 256 + threadIdx.x;
    dst[e] = f2bf(btab[(size_t)pos[e] * (NW * NH) + wh]);
  }
}

// ---------------------------------------------------------------------------
// Kernel 1: QKV GEMM, single-pass A panel.  M=69120 (540 blocks x 128 rows),
// N=576 (9 n-tiles inner loop), K=192 staged FULL-K in LDS once (fp32->bf16
// fused into staging).  B fragments read directly from global (W is 221 KB,
// L1/L2-resident).  One barrier per block.
// Wave tile: rows (w&1)*64 + 4x16, cols (w>>1)*32 + 2x16 of each 64-wide n-tile.
// ---------------------------------------------------------------------------
__global__ __launch_bounds__(256) void qkv_gemm_k(
    const float* __restrict__ X, const unsigned short* __restrict__ W,
    const float* __restrict__ Bv,
    unsigned short* __restrict__ qb, unsigned short* __restrict__ kb,
    unsigned short* __restrict__ vb) {
  __shared__ unsigned short As[128 * 200];   // stride 200 shorts (400 B)
  const int t    = threadIdx.x;
  const int m0   = blockIdx.x * 128;
  const int w    = t >> 6;
  const int lane = t & 63;
  const int ln15 = lane & 15;
  const int quad = lane >> 4;
  const int wm   = (w & 1) * 64;
  const int wn   = (w >> 1) * 32;

  // stage A full-K, converting fp32 -> bf16.  3072 octets, 12 iters.
  for (int it = t; it < 3072; it += 256) {
    const int row = it / 24;
    const int c8  = (it % 24) * 8;
    const float4 a = *(const float4*)(X + (size_t)(m0 + row) * 192 + c8);
    const float4 b = *(const float4*)(X + (size_t)(m0 + row) * 192 + c8 + 4);
    u16x8 u = {f2bf(a.x), f2bf(a.y), f2bf(a.z), f2bf(a.w),
               f2bf(b.x), f2bf(b.y), f2bf(b.z), f2bf(b.w)};
    *(u16x8*)&As[row * 200 + c8] = u;
  }
  __syncthreads();

  for (int nt = 0; nt < 9; ++nt) {
    const int col16_0 = nt * 64 + wn;          // base col of ntj=0 strip

    f32x4 acc[4][2];
#pragma unroll
    for (int mt = 0; mt < 4; ++mt)
#pragma unroll
      for (int ntj = 0; ntj < 2; ++ntj) acc[mt][ntj] = (f32x4){0.f, 0.f, 0.f, 0.f};

#pragma unroll
    for (int ks = 0; ks < 6; ++ks) {
      bf16x8 bf[2];
#pragma unroll
      for (int ntj = 0; ntj < 2; ++ntj)
        bf[ntj] = *(const bf16x8*)&W[(size_t)(col16_0 + ntj * 16 + ln15) * 192 +
                                     ks * 32 + quad * 8];
      bf16x8 af[4];
#pragma unroll
      for (int mt = 0; mt < 4; ++mt)
        af[mt] = *(bf16x8*)&As[(wm + mt * 16 + ln15) * 200 + ks * 32 + quad * 8];
#pragma unroll
      for (int mt = 0; mt < 4; ++mt)
#pragma unroll
        for (int ntj = 0; ntj < 2; ++ntj)
          acc[mt][ntj] = __builtin_amdgcn_mfma_f32_16x16x32_bf16(
              af[mt], bf[ntj], acc[mt][ntj], 0, 0, 0);
    }

    // epilogue for this n-tile
#pragma unroll
    for (int ntj = 0; ntj < 2; ++ntj) {
      const int col16 = col16_0 + ntj * 16;
      const int s     = col16 / 192;
      const int rem16 = col16 % 192;
      const int h     = (rem16 + ln15) >> 5;   // strip of 16 never crosses 32
      const int dd    = (rem16 + ln15) & 31;
      const float sc2 = (s == 0) ? SCALE : 1.0f;
      const float bias = Bv[col16 + ln15];
      unsigned short* dst = (s == 0) ? qb : (s == 1 ? kb : vb);
#pragma unroll
      for (int mt = 0; mt < 4; ++mt) {
#pragma unroll
        for (int r = 0; r < 4; ++r) {
          const int m  = m0 + wm + mt * 16 + quad * 4 + r;
          const int bw = m / NTOK;
          const int n  = m % NTOK;
          const unsigned short val = f2bf((acc[mt][ntj][r] + bias) * sc2);
          if (s < 2)
            dst[((size_t)(bw * NH + h) * NTOK + n) * HD + dd] = val;   // [bw,h,n,d]
          else
            dst[((size_t)(bw * NH + h) * HD + dd) * NTOK + n] = val;   // [bw,h,d,n]
        }
      }
    }
  }
}

// ---------------------------------------------------------------------------
// Kernel 2: MFMA attention, LDS-resident K/V (unchanged from R6).
// ---------------------------------------------------------------------------
__global__ __launch_bounds__(192, 3) void attn_k(
    const unsigned short* __restrict__ qbuf, const unsigned short* __restrict__ kbuf,
    const unsigned short* __restrict__ vbuf, const float* __restrict__ mask,
    const unsigned short* __restrict__ biasb, unsigned short* __restrict__ ao) {
  __shared__ unsigned short Ks[NTOK * 36];
  __shared__ unsigned short Vs[32 * 160];
  __shared__ unsigned short Ps[3 * 16 * 168];

  const int t    = threadIdx.x;
  const int wave = t / 64;
  const int lane = t & 63;
  const int ln15 = lane & 15;
  const int quad = lane >> 4;
  const int idx  = blockIdx.x;
  const int h    = idx / 480;
  const int bw   = idx % 480;
  const int w    = bw & 31;
  const int wh   = w * NH + h;
  const size_t hb = (size_t)(bw * NH + h) * (NTOK * HD);
  const unsigned short* qh = qbuf + hb;
  const float* maskp = mask + (size_t)bw * NN;
  const unsigned short* biasp = biasb + (size_t)wh * NN;
  unsigned short* ps = &Ps[wave * 16 * 168];

  for (int it = t; it < 576; it += 192) {
    const int row = it >> 2;
    const int col = (it & 3) * 8;
    *(u16x8*)&Ks[row * 36 + col] = *(const u16x8*)&kbuf[hb + row * HD + col];
  }
  for (int it = t; it < 576; it += 192) {
    const int row = it / 18;
    const int col = (it % 18) * 8;
    *(u16x8*)&Vs[row * 160 + col] = *(const u16x8*)&vbuf[hb + row * NTOK + col];
  }
  if (t < 64) {
    u16x8 z = {0, 0, 0, 0, 0, 0, 0, 0};
    *(u16x8*)&Vs[(t >> 1) * 160 + 144 + (t & 1) * 8] = z;
  }
  {
    ushort4 z = {0, 0, 0, 0};
    *(ushort4*)&ps[(lane >> 2) * 168 + 144 + (lane & 3) * 4] = z;
  }
  __syncthreads();

  for (int g = wave * 3; g < wave * 3 + 3; ++g) {
    const int i0 = g * 16;
    const int ib = i0 + quad * 4;

    const bf16x8 qf = *(const bf16x8*)&qh[(i0 + ln15) * HD + quad * 8];
    f32x4 s[9];
#pragma unroll
    for (int jt = 0; jt < 9; ++jt) {
      const bf16x8 kf = *(const bf16x8*)&Ks[(jt * 16 + ln15) * 36 + quad * 8];
      s[jt] = (f32x4){0.f, 0.f, 0.f, 0.f};
      s[jt] = __builtin_amdgcn_mfma_f32_16x16x32_bf16(qf, kf, s[jt], 0, 0, 0);
    }

#pragma unroll
    for (int jt = 0; jt < 9; ++jt) {
      const int j = jt * 16 + ln15;
#pragma unroll
      for (int r = 0; r < 4; ++r) {
        const int ij = (ib + r) * NTOK + j;
        s[jt][r] += bf2f(biasp[ij]) + maskp[ij];
      }
    }

    float rinv[4];
#pragma unroll
    for (int r = 0; r < 4; ++r) {
      float mx = s[0][r];
#pragma unroll
      for (int jt = 1; jt < 9; ++jt) mx = fmaxf(mx, s[jt][r]);
#pragma unroll
      for (int off = 1; off < 16; off <<= 1) mx = fmaxf(mx, __shfl_xor(mx, off));
      float sum = 0.f;
#pragma unroll
      for (int jt = 0; jt < 9; ++jt) {
        const float e = __expf(s[jt][r] - mx);
        s[jt][r] = e;
        sum += e;
      }
#pragma unroll
      for (int off = 1; off < 16; off <<= 1) sum += __shfl_xor(sum, off);
      rinv[r] = 1.0f / sum;
    }

#pragma unroll
    for (int jt = 0; jt < 9; ++jt)
#pragma unroll
      for (int r = 0; r < 4; ++r)
        ps[(quad * 4 + r) * 168 + jt * 16 + ln15] = f2bf(s[jt][r]);

    f32x4 o[2] = {{0.f, 0.f, 0.f, 0.f}, {0.f, 0.f, 0.f, 0.f}};
#pragma unroll
    for (int kt = 0; kt < 5; ++kt) {
      const bf16x8 pf = *(const bf16x8*)&ps[ln15 * 168 + kt * 32 + quad * 8];
#pragma unroll
      for (int nt = 0; nt < 2; ++nt) {
        const bf16x8 vf = *(const bf16x8*)&Vs[(nt * 16 + ln15) * 160 + kt * 32 + quad * 8];
        o[nt] = __builtin_amdgcn_mfma_f32_16x16x32_bf16(pf, vf, o[nt], 0, 0, 0);
      }
    }

#pragma unroll
    for (int nt = 0; nt < 2; ++nt)
#pragma unroll
      for (int r = 0; r < 4; ++r)
        ao[(size_t)(bw * NTOK + ib + r) * DIM + h * HD + nt * 16 + ln15] =
            f2bf(o[nt][r] * rinv[r]);
  }
}

// ---------------------------------------------------------------------------
// Kernel 3: proj GEMM, single-pass A panel.  M=69120 (540x128), N=192
// (3 n-tiles), K=192 full-K LDS.  B from global (73 KB, L1-resident).
// ---------------------------------------------------------------------------
__global__ __launch_bounds__(256) void proj_gemm_k(
    const unsigned short* __restrict__ AO, const unsigned short* __restrict__ W,
    const float* __restrict__ Bv, float* __restrict__ out) {
  __shared__ unsigned short As[128 * 200];
  const int t    = threadIdx.x;
  const int m0   = blockIdx.x * 128;
  const int w    = t >> 6;
  const int lane = t & 63;
  const int ln15 = lane & 15;
  const int quad = lane >> 4;
  const int wm   = (w & 1) * 64;
  const int wn   = (w >> 1) * 32;

  for (int it = t; it < 3072; it += 256) {
    const int row = it / 24;
    const int c8  = (it % 24) * 8;
    *(u16x8*)&As[row * 200 + c8] =
        *(const u16x8*)&AO[(size_t)(m0 + row) * 192 + c8];
  }
  __syncthreads();

  for (int nt = 0; nt < 3; ++nt) {
    const int col16_0 = nt * 64 + wn;

    f32x4 acc[4][2];
#pragma unroll
    for (int mt = 0; mt < 4; ++mt)
#pragma unroll
      for (int ntj = 0; ntj < 2; ++ntj) acc[mt][ntj] = (f32x4){0.f, 0.f, 0.f, 0.f};

#pragma unroll
    for (int ks = 0; ks < 6; ++ks) {
      bf16x8 bf[2];
#pragma unroll
      for (int ntj = 0; ntj < 2; ++ntj)
        bf[ntj] = *(const bf16x8*)&W[(size_t)(col16_0 + ntj * 16 + ln15) * 192 +
                                     ks * 32 + quad * 8];
      bf16x8 af[4];
#pragma unroll
      for (int mt = 0; mt < 4; ++mt)
        af[mt] = *(bf16x8*)&As[(wm + mt * 16 + ln15) * 200 + ks * 32 + quad * 8];
#pragma unroll
      for (int mt = 0; mt < 4; ++mt)
#pragma unroll
        for (int ntj = 0; ntj < 2; ++ntj)
          acc[mt][ntj] = __builtin_amdgcn_mfma_f32_16x16x32_bf16(
              af[mt], bf[ntj], acc[mt][ntj], 0, 0, 0);
    }

#pragma unroll
    for (int ntj = 0; ntj < 2; ++ntj) {
      const int colg = col16_0 + ntj * 16 + ln15;
      const float bias = Bv[colg];
#pragma unroll
      for (int mt = 0; mt < 4; ++mt) {
#pragma unroll
        for (int r = 0; r < 4; ++r) {
          const int m = m0 + wm + mt * 16 + quad * 4 + r;
          out[(size_t)m * 192 + colg] = acc[mt][ntj][r] + bias;
        }
      }
    }
  }
}

// ---------------------------------------------------------------------------
extern "C" void kernel_launch(void* const* d_in, const int* in_sizes, int n_in,
                              void* d_out, int out_size, void* d_ws, size_t ws_size,
                              hipStream_t stream) {
  const float* x      = (const float*)d_in[0];
  const float* mask   = (const float*)d_in[1];
  const float* qkv_w  = (const float*)d_in[2];
  const float* qkv_b  = (const float*)d_in[3];
  const float* proj_w = (const float*)d_in[4];
  const float* proj_b = (const float*)d_in[5];
  const float* btab   = (const float*)d_in[6];
  const int*   pos    = (const int*)d_in[7];
  float* out = (float*)d_out;

  unsigned short* ws = (unsigned short*)d_ws;
  const size_t sz = (size_t)MROWS * DIM;   // 13,271,040 elements
  unsigned short* qbuf  = ws;
  unsigned short* kbuf  = ws + sz;
  unsigned short* vbuf  = ws + 2 * sz;
  unsigned short* aobuf = ws + 3 * sz + 256;
  unsigned short* biasb = ws + 4 * sz + 1024;           // 192*20736 bf16 = 8 MB
  unsigned short* qwbf  = biasb + (size_t)192 * NN;
  unsigned short* pwbf  = qwbf + (size_t)K3 * DIM;

  conv_bf_k<<<(NQ8 + NP8) / 256, 256, 0, stream>>>(qkv_w, proj_w, qwbf, pwbf);
  bias_pre_k<<<dim3(NW * NH, 9), 256, 0, stream>>>(btab, pos, biasb);
  qkv_gemm_k<<<MROWS / 128, 256, 0, stream>>>(
      x, qwbf, qkv_b, qbuf, kbuf, vbuf);
  attn_k<<<NH * 480, 192, 0, stream>>>(
      qbuf, kbuf, vbuf, mask, biasb, aobuf);
  proj_gemm_k<<<MROWS / 128, 256, 0, stream>>>(
      aobuf, pwbf, proj_b, out);
}